// Round 4
// baseline (369.140 us; speedup 1.0000x reference)
//
#include <hip/hip_runtime.h>
#include <hip/hip_bf16.h>
#include <math.h>

#define BATCH 4096
#define IDIM 78
#define DM 256
#define DI 1024
#define NL 4

typedef __attribute__((ext_vector_type(8))) short bf16x8;
typedef __attribute__((ext_vector_type(4))) float f32x4;

__device__ __forceinline__ float siluf(float v){ return v / (1.0f + __expf(-v)); }
__device__ __forceinline__ float softplusf(float v){ return (v > 20.0f) ? v : log1pf(__expf(v)); }
__device__ __forceinline__ ushort f2bf(float f){
  union { float f; unsigned u; } c; c.f = f;
  unsigned r = c.u + 0x7fff + ((c.u >> 16) & 1);
  return (ushort)(r >> 16);
}
__device__ __forceinline__ float bf2f(ushort b){
  union { unsigned u; float f; } c; c.u = ((unsigned)b) << 16; return c.f;
}
__device__ __forceinline__ unsigned pack2(float lo, float hi){
  return (unsigned)f2bf(lo) | ((unsigned)f2bf(hi) << 16);
}
// async global->LDS, 16B per lane; LDS dest is wave-uniform base + lane*16
__device__ __forceinline__ void async_copy16(void* lds, const void* g){
  __builtin_amdgcn_global_load_lds(
      (const __attribute__((address_space(1))) unsigned int*)g,
      (__attribute__((address_space(3))) unsigned int*)lds, 16, 0, 0);
}

// ---------- transpose + fp32->bf16: dst[C][R] = bf16(src[R][C]) ----------
template<int R, int C>
__global__ __launch_bounds__(256) void k_tconv(const float* __restrict__ src, ushort* __restrict__ dst){
  __shared__ float tile[32][33];
  int c0 = blockIdx.x*32, r0 = blockIdx.y*32;
  src += (size_t)blockIdx.z * R * C;
  dst += (size_t)blockIdx.z * R * C;
  int t = threadIdx.x;
  int ci = t & 31, rq = t >> 5;
  #pragma unroll
  for (int p=0;p<4;p++){ int ri = p*8 + rq; tile[ri][ci] = src[(size_t)(r0+ri)*C + c0 + ci]; }
  __syncthreads();
  #pragma unroll
  for (int p=0;p<4;p++){ int ri = p*8 + rq; dst[(size_t)(c0+ri)*R + r0 + ci] = f2bf(tile[ci][ri]); }
}

// ---------- WxT[l][80][1024] = bf16(Wx[l][1024][80]^T) ----------
__global__ __launch_bounds__(256) void k_wxT(const float* __restrict__ Wx, ushort* __restrict__ WxT){
  int l = blockIdx.z;
  int n = blockIdx.y;
  int k = blockIdx.x*256 + threadIdx.x;
  WxT[(size_t)l*80*DI + (size_t)n*DI + k] = f2bf(Wx[(size_t)l*DI*80 + (size_t)k*80 + n]);
}

// ---------- proj_in: h = x @ Wp + bp (fp32) ----------
__global__ __launch_bounds__(256) void k_proj_in(const float* __restrict__ x,
    const float* __restrict__ Wp, const float* __restrict__ bp, float* __restrict__ h){
  int b = blockIdx.x, t = threadIdx.x;
  __shared__ float xs[IDIM];
  if (t < IDIM) xs[t] = x[b*IDIM + t];
  __syncthreads();
  float acc = bp[t];
  #pragma unroll
  for (int k=0;k<IDIM;k++) acc = fmaf(xs[k], Wp[k*DM + t], acc);
  h[b*DM + t] = acc;
}

// ---------- k_blk0: fused rmsnorm + bf16 MFMA GEMM (xn @ WinT^T) + conv/silu epilogue ----------
// A-panel (128 x 256) built in LDS from fp32 h with in-kernel rmsnorm; B streamed, 2ph prefetch.
__global__ __launch_bounds__(256) void k_blk0(
    const float* __restrict__ h, const float* __restrict__ nw,
    const ushort* __restrict__ Bt,   // WinT [2048][256]
    const float* __restrict__ cwl, const float* __restrict__ cbl,
    ushort* __restrict__ xi, ushort* __restrict__ sz)
{
  __shared__ __align__(16) ushort Apan[128*256];   // 64 KB, chunk-XOR swizzled
  __shared__ __align__(16) ushort Bs[2][128][32];  // 16 KB double-buffer
  int t = threadIdx.x;
  int row0 = blockIdx.x*128, col0 = blockIdx.y*128;
  int wid = t>>6, lane = t&63;
  int wr = wid>>1, wc = wid&1, lr = lane&15, lk = lane>>4;
  int sr = lane>>2, scn = lane&3;
  int gch = scn ^ (sr&3);
  int rsw = (lk ^ (lr&3))*8;

  // prologue: A panel with fused rmsnorm (2 threads per row, 128 cols each)
  {
    int r = t>>1, hf = t&1;
    const float4* hv = (const float4*)(h + (size_t)(row0 + r)*DM + hf*128);
    float ssq = 0.f;
    #pragma unroll 8
    for (int i=0;i<32;i++){ float4 v = hv[i]; ssq += v.x*v.x + v.y*v.y + v.z*v.z + v.w*v.w; }
    ssq += __shfl_xor(ssq, 1);
    float scale = rsqrtf(ssq*(1.0f/DM) + 1e-5f);
    const float4* nv = (const float4*)(nw + hf*128);
    ushort* arow = Apan + r*256;
    int r7 = r&7;
    #pragma unroll 4
    for (int j=0;j<16;j++){
      float4 a = hv[2*j], b = hv[2*j+1];
      float4 na = nv[2*j], nb = nv[2*j+1];
      uint4 w;
      w.x = pack2(a.x*scale*na.x, a.y*scale*na.y);
      w.y = pack2(a.z*scale*na.z, a.w*scale*na.w);
      w.z = pack2(b.x*scale*nb.x, b.y*scale*nb.y);
      w.w = pack2(b.z*scale*nb.z, b.w*scale*nb.w);
      int k8 = hf*16 + j;
      *(uint4*)&arow[(k8 ^ r7)*8] = w;
    }
  }
  // stage B buf0
  const ushort* Bb = Bt + (size_t)(col0 + sr)*DM + gch*8;
  #pragma unroll
  for (int q=0;q<2;q++){ int i=q*4+wid; async_copy16(&Bs[0][i*16][0], Bb + (size_t)i*16*DM); }
  __syncthreads();

  f32x4 acc[4][4] = {};
  int cur = 0;
  for (int tt=0; tt<8; ++tt){
    if (tt<7){
      #pragma unroll
      for (int q=0;q<2;q++){ int i=q*4+wid; async_copy16(&Bs[cur^1][i*16][0], Bb + (size_t)i*16*DM + (tt+1)*32); }
    }
    bf16x8 av[4], bv[4];
    #pragma unroll
    for (int i=0;i<4;i++){
      int rr = wr*64 + i*16 + lr;
      av[i] = *(const bf16x8*)&Apan[rr*256 + (((4*tt + lk) ^ (lr&7))*8)];
    }
    #pragma unroll
    for (int j=0;j<4;j++) bv[j] = *(const bf16x8*)&Bs[cur][wc*64 + j*16 + lr][rsw];
    #pragma unroll
    for (int i=0;i<4;i++)
      #pragma unroll
      for (int j=0;j<4;j++)
        acc[i][j] = __builtin_amdgcn_mfma_f32_16x16x32_bf16(av[i], bv[j], acc[i][j], 0,0,0);
    __syncthreads();
    cur ^= 1;
  }

  #pragma unroll
  for (int i=0;i<4;i++)
    #pragma unroll
    for (int j=0;j<4;j++){
      int colb = col0 + wc*64 + j*16 + lr;
      #pragma unroll
      for (int r=0;r<4;r++){
        int rowb = row0 + wr*64 + i*16 + lk*4 + r;
        float v = acc[i][j][r];
        if (colb < DI) xi[(size_t)rowb*DI + colb] = f2bf(siluf(fmaf(cwl[colb*16+15], v, cbl[colb])));
        else           sz[(size_t)rowb*DI + colb - DI] = f2bf(siluf(v));
      }
    }
}

// ---------- k_ssm: fused dbc (MFMA, in-block split-K) + delta + gating; y written in-place over xi ----------
__global__ __launch_bounds__(512) void k_ssm(const ushort* __restrict__ xi, const ushort* __restrict__ sz,
    const ushort* __restrict__ WxT, const float* __restrict__ Wdt, const float* __restrict__ bdt,
    const float* __restrict__ Dd, ushort* __restrict__ y){
  __shared__ float dsum[8][16][81];
  __shared__ float sS[16];
  int r0 = blockIdx.x*16;
  int t = threadIdx.x, w = t>>6, lane = t&63, lr = lane&15, lk = lane>>4;
  // phase 1: dbc[16][80] = xi[16 rows][1024] @ WxT[80][1024]^T, wave w owns k in [w*128, +128)
  f32x4 acc[5] = {};
  const ushort* Ab = xi  + (size_t)(r0+lr)*DI + w*128 + lk*8;
  const ushort* Bb = WxT + (size_t)lr*DI      + w*128 + lk*8;
  #pragma unroll
  for (int s=0;s<4;s++){
    bf16x8 a = *(const bf16x8*)(Ab + s*32);
    #pragma unroll
    for (int j=0;j<5;j++){
      bf16x8 b = *(const bf16x8*)(Bb + (size_t)j*16*DI + s*32);
      acc[j] = __builtin_amdgcn_mfma_f32_16x16x32_bf16(a, b, acc[j], 0,0,0);
    }
  }
  #pragma unroll
  for (int j=0;j<5;j++)
    #pragma unroll
    for (int r=0;r<4;r++)
      dsum[w][lk*4+r][j*16+lr] = acc[j][r];
  __syncthreads();
  for (int idx=t; idx<16*80; idx+=512){
    int rr = idx/80, n = idx%80;
    float s = dsum[0][rr][n];
    #pragma unroll
    for (int q=1;q<8;q++) s += dsum[q][rr][n];
    dsum[0][rr][n] = s;
  }
  __syncthreads();
  if (t < 256){
    int row = t>>4, ln = t&15;
    float p = dsum[0][row][16+ln]*dsum[0][row][48+ln]
            + dsum[0][row][32+ln]*dsum[0][row][64+ln];
    p += __shfl_xor(p, 8); p += __shfl_xor(p, 4); p += __shfl_xor(p, 2); p += __shfl_xor(p, 1);
    if (ln==0) sS[row] = p;
  }
  __syncthreads();
  // phase 2: per (row, e): delta = softplus(bdt[e] + dbc[row,:16]@Wdt[:,e]); y = xi*(delta*s+D)*sz
  int e = 2*t;
  float2 wdtr[16];
  #pragma unroll
  for (int r=0;r<16;r++) wdtr[r] = *(const float2*)(Wdt + (size_t)r*DI + e);
  float2 bd = *(const float2*)(bdt + e);
  float2 dd = *(const float2*)(Dd + e);
  for (int row=0; row<16; ++row){
    float u0 = bd.x, u1 = bd.y;
    #pragma unroll
    for (int r=0;r<16;r++){ float dv = dsum[0][row][r]; u0 = fmaf(wdtr[r].x, dv, u0); u1 = fmaf(wdtr[r].y, dv, u1); }
    float srow = sS[row];
    float d0 = softplusf(u0), d1 = softplusf(u1);
    size_t o = (size_t)(r0+row)*DI + e;
    ushort2 xv = *(const ushort2*)(xi + o);
    ushort2 zv = *(const ushort2*)(sz + o);
    ushort2 ov;
    ov.x = f2bf(bf2f(xv.x) * fmaf(d0, srow, dd.x) * bf2f(zv.x));
    ov.y = f2bf(bf2f(xv.y) * fmaf(d1, srow, dd.y) * bf2f(zv.y));
    *(ushort2*)(y + o) = ov;
  }
}

// ---------- k_blk1: bf16 MFMA GEMM (y @ WoutT^T), 2ph prefetch, residual += into h ----------
__global__ __launch_bounds__(256) void k_blk1(
    const ushort* __restrict__ A, const ushort* __restrict__ Bt, float* __restrict__ hout)
{
  __shared__ __align__(16) ushort As[2][64][32];
  __shared__ __align__(16) ushort Bs[2][64][32];
  int t = threadIdx.x;
  int row0 = blockIdx.x*64, col0 = blockIdx.y*64;
  int wid = t>>6, lane = t&63;
  int wr = wid>>1, wc = wid&1, lr = lane&15, lk = lane>>4;
  int sr = lane>>2, scn = lane&3;
  int gch = scn ^ (sr&3);
  int rsw = (lk ^ (lr&3))*8;
  const ushort* Ab = A  + (size_t)(row0 + sr)*DI + gch*8;
  const ushort* Bb = Bt + (size_t)(col0 + sr)*DI + gch*8;
  async_copy16(&As[0][wid*16][0], Ab + (size_t)wid*16*DI);
  async_copy16(&Bs[0][wid*16][0], Bb + (size_t)wid*16*DI);
  __syncthreads();
  f32x4 acc[2][2] = {};
  int cur = 0;
  for (int tt=0; tt<32; ++tt){
    if (tt<31){
      async_copy16(&As[cur^1][wid*16][0], Ab + (size_t)wid*16*DI + (tt+1)*32);
      async_copy16(&Bs[cur^1][wid*16][0], Bb + (size_t)wid*16*DI + (tt+1)*32);
    }
    bf16x8 av[2], bv[2];
    #pragma unroll
    for (int i=0;i<2;i++) av[i] = *(const bf16x8*)&As[cur][wr*32 + i*16 + lr][rsw];
    #pragma unroll
    for (int j=0;j<2;j++) bv[j] = *(const bf16x8*)&Bs[cur][wc*32 + j*16 + lr][rsw];
    #pragma unroll
    for (int i=0;i<2;i++)
      #pragma unroll
      for (int j=0;j<2;j++)
        acc[i][j] = __builtin_amdgcn_mfma_f32_16x16x32_bf16(av[i], bv[j], acc[i][j], 0,0,0);
    __syncthreads();
    cur ^= 1;
  }
  #pragma unroll
  for (int i=0;i<2;i++)
    #pragma unroll
    for (int j=0;j<2;j++){
      int colb = col0 + wc*32 + j*16 + lr;
      #pragma unroll
      for (int r=0;r<4;r++){
        int rowb = row0 + wr*32 + i*16 + lk*4 + r;
        hout[(size_t)rowb*DM + colb] += acc[i][j][r];
      }
    }
}

// ---------- final: out = sigmoid(h @ Wf + bf) ----------
__global__ __launch_bounds__(64) void k_final(const float* __restrict__ h,
    const float* __restrict__ Wf, const float* __restrict__ bf, float* __restrict__ out){
  int b = blockIdx.x, t = threadIdx.x;
  float p = 0.0f;
  #pragma unroll
  for (int q=0;q<4;q++){ int c = q*64 + t; p = fmaf(h[(size_t)b*DM + c], Wf[c], p); }
  #pragma unroll
  for (int o=32;o>0;o>>=1) p += __shfl_down(p,o);
  if (t==0) out[b] = 1.0f/(1.0f + __expf(-(p + bf[0])));
}

extern "C" void kernel_launch(void* const* d_in, const int* in_sizes, int n_in,
                              void* d_out, int out_size, void* d_ws, size_t ws_size,
                              hipStream_t stream){
  const float* x   = (const float*)d_in[0];
  const float* Wp  = (const float*)d_in[1];
  const float* bp  = (const float*)d_in[2];
  const float* nw  = (const float*)d_in[3];
  const float* Win = (const float*)d_in[4];
  const float* cw  = (const float*)d_in[5];
  const float* cb  = (const float*)d_in[6];
  const float* Wx  = (const float*)d_in[7];
  const float* Wdt = (const float*)d_in[8];
  const float* bdt = (const float*)d_in[9];
  const float* Dd  = (const float*)d_in[11];   // A_log (d_in[10]) is dead: scan length 1, h0 = 0
  const float* Wout= (const float*)d_in[12];
  const float* Wf  = (const float*)d_in[13];
  const float* bf  = (const float*)d_in[14];
  float* out = (float*)d_out;

  char* wsb = (char*)d_ws;
  float*  h    = (float*)wsb;  wsb += (size_t)BATCH*DM*4;          // 4 MB
  ushort* xi   = (ushort*)wsb; wsb += (size_t)BATCH*DI*2;          // 8 MB
  ushort* sz   = (ushort*)wsb; wsb += (size_t)BATCH*DI*2;          // 8 MB
  ushort* WinT = (ushort*)wsb; wsb += (size_t)NL*2*DI*DM*2;        // 4 MB
  ushort* WoutT= (ushort*)wsb; wsb += (size_t)NL*DM*DI*2;          // 2 MB
  ushort* WxT  = (ushort*)wsb; wsb += (size_t)NL*80*DI*2;          // 0.64 MB

  // weight prep
  k_tconv<DM, 2*DI><<<dim3(2*DI/32, DM/32, NL), 256, 0, stream>>>(Win, WinT);
  k_tconv<DI, DM><<<dim3(DM/32, DI/32, NL), 256, 0, stream>>>(Wout, WoutT);
  k_wxT<<<dim3(DI/256, 80, NL), 256, 0, stream>>>(Wx, WxT);

  k_proj_in<<<BATCH,256,0,stream>>>(x, Wp, bp, h);
  for (int l=0;l<NL;l++){
    k_blk0<<<dim3(BATCH/128, (2*DI)/128),256,0,stream>>>(
        h, nw + l*DM, WinT + (size_t)l*2*DI*DM,
        cw + (size_t)l*DI*16, cb + (size_t)l*DI, xi, sz);
    k_ssm<<<BATCH/16,512,0,stream>>>(xi, sz, WxT + (size_t)l*80*DI,
        Wdt + (size_t)l*16*DI, bdt + (size_t)l*DI, Dd + (size_t)l*DI, xi);
    k_blk1<<<dim3(BATCH/64, DM/64),256,0,stream>>>(
        xi, WoutT + (size_t)l*DM*DI, h);
  }
  k_final<<<BATCH,64,0,stream>>>(h, Wf, bf, out);
}

// Round 5
// 288.898 us; speedup vs baseline: 1.2778x; 1.2778x over previous
//
#include <hip/hip_runtime.h>
#include <hip/hip_bf16.h>
#include <math.h>

#define BATCH 4096
#define IDIM 78
#define DM 256
#define DI 1024
#define NL 4

typedef __attribute__((ext_vector_type(8))) short bf16x8;
typedef __attribute__((ext_vector_type(4))) float f32x4;

__device__ __forceinline__ float siluf(float v){ return v / (1.0f + __expf(-v)); }
__device__ __forceinline__ float softplusf(float v){ return (v > 20.0f) ? v : log1pf(__expf(v)); }
__device__ __forceinline__ ushort f2bf(float f){
  union { float f; unsigned u; } c; c.f = f;
  unsigned r = c.u + 0x7fff + ((c.u >> 16) & 1);
  return (ushort)(r >> 16);
}
__device__ __forceinline__ float bf2f(ushort b){
  union { unsigned u; float f; } c; c.u = ((unsigned)b) << 16; return c.f;
}
// async global->LDS, 16B per lane; LDS dest = wave-uniform base + lane*16
__device__ __forceinline__ void async_copy16(void* lds, const void* g){
  __builtin_amdgcn_global_load_lds(
      (const __attribute__((address_space(1))) unsigned int*)g,
      (__attribute__((address_space(3))) unsigned int*)lds, 16, 0, 0);
}

// ---------- fused weight prep: WinT, WoutT (32x32 transpose tiles) + WxT ----------
__device__ __forceinline__ void tconv_tile(const float* __restrict__ src, ushort* __restrict__ dst,
    int R, int C, int r0, int c0, float (*tile)[33]){
  int t = threadIdx.x, ci = t & 31, rq = t >> 5;
  #pragma unroll
  for (int p=0;p<4;p++){ int ri = p*8 + rq; tile[ri][ci] = src[(size_t)(r0+ri)*C + c0 + ci]; }
  __syncthreads();
  #pragma unroll
  for (int p=0;p<4;p++){ int ri = p*8 + rq; dst[(size_t)(c0+ri)*R + r0 + ci] = f2bf(tile[ci][ri]); }
}

__global__ __launch_bounds__(256) void k_prep(const float* __restrict__ Win,
    const float* __restrict__ Wout, const float* __restrict__ Wx,
    ushort* __restrict__ WinT, ushort* __restrict__ WoutT, ushort* __restrict__ WxT){
  __shared__ float tile[32][33];
  int bid = blockIdx.x;
  if (bid < 2048){                       // Win [l][256][2048] -> WinT [l][2048][256]
    int x = bid & 63, y = (bid >> 6) & 7, l = bid >> 9;
    tconv_tile(Win + (size_t)l*DM*2*DI, WinT + (size_t)l*2*DI*DM, DM, 2*DI, y*32, x*32, tile);
  } else if (bid < 3072){                // Wout [l][1024][256] -> WoutT [l][256][1024]
    int b = bid - 2048;
    int x = b & 7, y = (b >> 3) & 31, l = b >> 8;
    tconv_tile(Wout + (size_t)l*DI*DM, WoutT + (size_t)l*DM*DI, DI, DM, y*32, x*32, tile);
  } else {                               // Wx [l][1024][80] -> WxT [l][80][1024]
    int b = bid - 3072;
    int x = b & 3, y = (b >> 2) % 80, l = b / 320;
    int k = x*256 + threadIdx.x;
    WxT[(size_t)l*80*DI + (size_t)y*DI + k] = f2bf(Wx[(size_t)l*DI*80 + (size_t)k*80 + y]);
  }
}

// ---------- proj_in + rmsnorm(layer0): h = x@Wp+bp ; xn = rms(h)*nw ----------
__global__ __launch_bounds__(256) void k_proj_in(const float* __restrict__ x,
    const float* __restrict__ Wp, const float* __restrict__ bp,
    const float* __restrict__ nw, float* __restrict__ h, ushort* __restrict__ xn){
  int b = blockIdx.x, t = threadIdx.x;
  __shared__ float xs[IDIM];
  if (t < IDIM) xs[t] = x[b*IDIM + t];
  __syncthreads();
  float acc = bp[t];
  #pragma unroll
  for (int k=0;k<IDIM;k++) acc = fmaf(xs[k], Wp[k*DM + t], acc);
  h[b*DM + t] = acc;
  float ss = acc*acc;
  #pragma unroll
  for (int o=32;o>0;o>>=1) ss += __shfl_down(ss, o);
  __shared__ float red[4];
  if ((t&63)==0) red[t>>6] = ss;
  __syncthreads();
  float tot = red[0]+red[1]+red[2]+red[3];
  float sc = rsqrtf(tot*(1.0f/DM) + 1e-5f);
  xn[b*DM + t] = f2bf(acc*sc*nw[t]);
}

// ---------- k_blk0: xn @ WinT^T -> conv/silu epilogue. 128x128 tile, BK=64, 2ph, XOR-8 swizzle ----------
__global__ __launch_bounds__(256) void k_blk0(
    const ushort* __restrict__ A,     // xn [4096][256]
    const ushort* __restrict__ Bt,    // WinT [2048][256]
    const float* __restrict__ cwl, const float* __restrict__ cbl,
    ushort* __restrict__ xi, ushort* __restrict__ sz)
{
  __shared__ __align__(16) ushort As[2][128][64];   // 32 KB
  __shared__ __align__(16) ushort Bs[2][128][64];   // 32 KB
  int t = threadIdx.x;
  int row0 = blockIdx.x*128, col0 = blockIdx.y*128;
  int wid = t>>6, lane = t&63;
  int wr = wid>>1, wc = wid&1, lr = lane&15, lk = lane>>4;
  int srow = lane>>3;                  // 0..7 (row within an 8-row op)
  int g = (lane&7) ^ srow;             // pre-swizzled source chunk (XOR-8)
  const ushort* Ab = A  + (size_t)(row0 + srow)*DM + g*8;
  const ushort* Bb = Bt + (size_t)(col0 + srow)*DM + g*8;

  f32x4 acc[4][4] = {};
  #define STAGE0(buf, tt) { \
    _Pragma("unroll") \
    for (int q=0;q<4;q++){ int i = q*4 + wid; \
      async_copy16(&As[buf][i*8][0], Ab + (size_t)i*8*DM + (tt)*64); \
      async_copy16(&Bs[buf][i*8][0], Bb + (size_t)i*8*DM + (tt)*64); } }

  STAGE0(0, 0);
  __syncthreads();
  int cur = 0;
  for (int tt=0; tt<4; ++tt){
    if (tt < 3) STAGE0(cur^1, tt+1);
    #pragma unroll
    for (int win=0; win<2; ++win){
      int sl = ((win*4 + lk) ^ (lr&7))*8;
      bf16x8 av[4], bv[4];
      #pragma unroll
      for (int i=0;i<4;i++) av[i] = *(const bf16x8*)&As[cur][wr*64 + i*16 + lr][sl];
      #pragma unroll
      for (int j=0;j<4;j++) bv[j] = *(const bf16x8*)&Bs[cur][wc*64 + j*16 + lr][sl];
      #pragma unroll
      for (int i=0;i<4;i++)
        #pragma unroll
        for (int j=0;j<4;j++)
          acc[i][j] = __builtin_amdgcn_mfma_f32_16x16x32_bf16(av[i], bv[j], acc[i][j], 0,0,0);
    }
    __syncthreads();
    cur ^= 1;
  }

  #pragma unroll
  for (int i=0;i<4;i++)
    #pragma unroll
    for (int j=0;j<4;j++){
      int colb = col0 + wc*64 + j*16 + lr;
      #pragma unroll
      for (int r=0;r<4;r++){
        int rowb = row0 + wr*64 + i*16 + lk*4 + r;
        float v = acc[i][j][r];
        if (colb < DI) xi[(size_t)rowb*DI + colb] = f2bf(siluf(fmaf(cwl[colb*16+15], v, cbl[colb])));
        else           sz[(size_t)rowb*DI + colb - DI] = f2bf(siluf(v));
      }
    }
}

// ---------- k_ssm: fused dbc (MFMA split-K in block) + delta + gating; in-place y over xi ----------
__global__ __launch_bounds__(512) void k_ssm(const ushort* __restrict__ xi, const ushort* __restrict__ sz,
    const ushort* __restrict__ WxT, const float* __restrict__ Wdt, const float* __restrict__ bdt,
    const float* __restrict__ Dd, ushort* __restrict__ y){
  __shared__ float dsum[8][16][81];
  __shared__ float sS[16];
  int r0 = blockIdx.x*16;
  int t = threadIdx.x, w = t>>6, lane = t&63, lr = lane&15, lk = lane>>4;
  f32x4 acc[5] = {};
  const ushort* Ab = xi  + (size_t)(r0+lr)*DI + w*128 + lk*8;
  const ushort* Bb = WxT + (size_t)lr*DI      + w*128 + lk*8;
  #pragma unroll
  for (int s=0;s<4;s++){
    bf16x8 a = *(const bf16x8*)(Ab + s*32);
    #pragma unroll
    for (int j=0;j<5;j++){
      bf16x8 b = *(const bf16x8*)(Bb + (size_t)j*16*DI + s*32);
      acc[j] = __builtin_amdgcn_mfma_f32_16x16x32_bf16(a, b, acc[j], 0,0,0);
    }
  }
  #pragma unroll
  for (int j=0;j<5;j++)
    #pragma unroll
    for (int r=0;r<4;r++)
      dsum[w][lk*4+r][j*16+lr] = acc[j][r];
  __syncthreads();
  for (int idx=t; idx<16*80; idx+=512){
    int rr = idx/80, n = idx%80;
    float s = dsum[0][rr][n];
    #pragma unroll
    for (int q=1;q<8;q++) s += dsum[q][rr][n];
    dsum[0][rr][n] = s;
  }
  __syncthreads();
  if (t < 256){
    int row = t>>4, ln = t&15;
    float p = dsum[0][row][16+ln]*dsum[0][row][48+ln]
            + dsum[0][row][32+ln]*dsum[0][row][64+ln];
    p += __shfl_xor(p, 8); p += __shfl_xor(p, 4); p += __shfl_xor(p, 2); p += __shfl_xor(p, 1);
    if (ln==0) sS[row] = p;
  }
  __syncthreads();
  int e = 2*t;
  float2 wdtr[16];
  #pragma unroll
  for (int r=0;r<16;r++) wdtr[r] = *(const float2*)(Wdt + (size_t)r*DI + e);
  float2 bd = *(const float2*)(bdt + e);
  float2 dd = *(const float2*)(Dd + e);
  for (int row=0; row<16; ++row){
    float u0 = bd.x, u1 = bd.y;
    #pragma unroll
    for (int r=0;r<16;r++){ float dv = dsum[0][row][r]; u0 = fmaf(wdtr[r].x, dv, u0); u1 = fmaf(wdtr[r].y, dv, u1); }
    float srow = sS[row];
    float d0 = softplusf(u0), d1 = softplusf(u1);
    size_t o = (size_t)(r0+row)*DI + e;
    ushort2 xv = *(const ushort2*)(xi + o);
    ushort2 zv = *(const ushort2*)(sz + o);
    ushort2 ov;
    ov.x = f2bf(bf2f(xv.x) * fmaf(d0, srow, dd.x) * bf2f(zv.x));
    ov.y = f2bf(bf2f(xv.y) * fmaf(d1, srow, dd.y) * bf2f(zv.y));
    *(ushort2*)(y + o) = ov;
  }
}

// ---------- k_blk1: y @ WoutT^T, h += ; epilogue computes rmsnorm->xn (or final sigmoid) ----------
// BM=16, BN=256 (full rows in-block), K=1024, BK=64, 2ph prefetch, XOR-8 swizzle
template<int LAST>
__global__ __launch_bounds__(256) void k_blk1(
    const ushort* __restrict__ A,    // y [4096][1024]
    const ushort* __restrict__ Bt,   // WoutT [256][1024]
    float* __restrict__ h,
    const float* __restrict__ nw,    // next layer norm weight (!LAST)
    const float* __restrict__ Wf, const float* __restrict__ bf,
    ushort* __restrict__ xn, float* __restrict__ out)
{
  __shared__ __align__(16) ushort As[2][16][64];    // 4 KB
  __shared__ __align__(16) ushort Bs[2][256][64];   // 64 KB
  __shared__ float sred[2][4][16];
  __shared__ float ssc[16];
  int t = threadIdx.x, wid = t>>6, lane = t&63, lr = lane&15, lk = lane>>4;
  int row0 = blockIdx.x*16;
  int srow = lane>>3, g = (lane&7) ^ srow;
  const ushort* Ab = A  + (size_t)(row0+srow)*DI + g*8;
  const ushort* Bb = Bt + (size_t)srow*DI + g*8;

  #define STAGE1(buf, tt) { \
    _Pragma("unroll") \
    for (int q=0;q<8;q++){ int i = q*4 + wid; \
      async_copy16(&Bs[buf][i*8][0], Bb + (size_t)i*8*DI + (tt)*64); } \
    if (wid < 2) async_copy16(&As[buf][wid*8][0], Ab + (size_t)wid*8*DI + (tt)*64); }

  STAGE1(0, 0);
  __syncthreads();
  f32x4 acc[4] = {};
  int cur = 0;
  for (int tt=0; tt<16; ++tt){
    if (tt < 15) STAGE1(cur^1, tt+1);
    #pragma unroll
    for (int win=0; win<2; ++win){
      int sl = ((win*4 + lk) ^ (lr&7))*8;
      bf16x8 a = *(const bf16x8*)&As[cur][lr][sl];
      #pragma unroll
      for (int j=0;j<4;j++){
        bf16x8 b = *(const bf16x8*)&Bs[cur][wid*64 + j*16 + lr][sl];
        acc[j] = __builtin_amdgcn_mfma_f32_16x16x32_bf16(a, b, acc[j], 0,0,0);
      }
    }
    __syncthreads();
    cur ^= 1;
  }

  // epilogue: residual add + per-row reduce (ssq, and final dot if LAST)
  float hv[4][4];
  float p[4] = {0,0,0,0}, pf[4] = {0,0,0,0};
  #pragma unroll
  for (int j=0;j<4;j++){
    int colb = wid*64 + j*16 + lr;
    #pragma unroll
    for (int r=0;r<4;r++){
      int rowb = lk*4 + r;
      size_t o = (size_t)(row0+rowb)*DM + colb;
      float v = h[o] + acc[j][r];
      if constexpr (!LAST) h[o] = v;
      hv[j][r] = v;
      p[r] += v*v;
      if constexpr (LAST) pf[r] += v * Wf[colb];
    }
  }
  #pragma unroll
  for (int r=0;r<4;r++){
    #pragma unroll
    for (int o=1;o<16;o<<=1){
      p[r] += __shfl_xor(p[r], o);
      if constexpr (LAST) pf[r] += __shfl_xor(pf[r], o);
    }
  }
  if (lr == 0){
    #pragma unroll
    for (int r=0;r<4;r++){
      sred[0][wid][lk*4+r] = p[r];
      if constexpr (LAST) sred[1][wid][lk*4+r] = pf[r];
    }
  }
  __syncthreads();
  if (t < 16){
    float tot = sred[0][0][t] + sred[0][1][t] + sred[0][2][t] + sred[0][3][t];
    ssc[t] = rsqrtf(tot*(1.0f/DM) + 1e-5f);
    if constexpr (LAST){
      float ft = sred[1][0][t] + sred[1][1][t] + sred[1][2][t] + sred[1][3][t];
      out[row0 + t] = 1.0f/(1.0f + __expf(-(ft + bf[0])));
    }
  }
  __syncthreads();
  if constexpr (!LAST){
    #pragma unroll
    for (int j=0;j<4;j++){
      int colb = wid*64 + j*16 + lr;
      float nwv = nw[colb];
      #pragma unroll
      for (int r=0;r<4;r++){
        int rowb = lk*4 + r;
        xn[(size_t)(row0+rowb)*DM + colb] = f2bf(hv[j][r]*ssc[rowb]*nwv);
      }
    }
  }
}

extern "C" void kernel_launch(void* const* d_in, const int* in_sizes, int n_in,
                              void* d_out, int out_size, void* d_ws, size_t ws_size,
                              hipStream_t stream){
  const float* x   = (const float*)d_in[0];
  const float* Wp  = (const float*)d_in[1];
  const float* bp  = (const float*)d_in[2];
  const float* nw  = (const float*)d_in[3];
  const float* Win = (const float*)d_in[4];
  const float* cw  = (const float*)d_in[5];
  const float* cb  = (const float*)d_in[6];
  const float* Wx  = (const float*)d_in[7];
  const float* Wdt = (const float*)d_in[8];
  const float* bdt = (const float*)d_in[9];
  const float* Dd  = (const float*)d_in[11];   // A_log (d_in[10]) is dead: scan length 1, h0 = 0
  const float* Wout= (const float*)d_in[12];
  const float* Wf  = (const float*)d_in[13];
  const float* bf  = (const float*)d_in[14];
  float* out = (float*)d_out;

  char* wsb = (char*)d_ws;
  float*  h    = (float*)wsb;  wsb += (size_t)BATCH*DM*4;          // 4 MB
  ushort* xn   = (ushort*)wsb; wsb += (size_t)BATCH*DM*2;          // 2 MB
  ushort* xi   = (ushort*)wsb; wsb += (size_t)BATCH*DI*2;          // 8 MB
  ushort* sz   = (ushort*)wsb; wsb += (size_t)BATCH*DI*2;          // 8 MB
  ushort* WinT = (ushort*)wsb; wsb += (size_t)NL*2*DI*DM*2;        // 4 MB
  ushort* WoutT= (ushort*)wsb; wsb += (size_t)NL*DM*DI*2;          // 2 MB
  ushort* WxT  = (ushort*)wsb; wsb += (size_t)NL*80*DI*2;          // 0.64 MB

  k_prep<<<4352, 256, 0, stream>>>(Win, Wout, Wx, WinT, WoutT, WxT);
  k_proj_in<<<BATCH, 256, 0, stream>>>(x, Wp, bp, nw, h, xn);
  for (int l=0;l<NL;l++){
    k_blk0<<<dim3(BATCH/128, (2*DI)/128), 256, 0, stream>>>(
        xn, WinT + (size_t)l*2*DI*DM,
        cw + (size_t)l*DI*16, cb + (size_t)l*DI, xi, sz);
    k_ssm<<<BATCH/16, 512, 0, stream>>>(xi, sz, WxT + (size_t)l*80*DI,
        Wdt + (size_t)l*16*DI, bdt + (size_t)l*DI, Dd + (size_t)l*DI, xi);
    if (l < NL-1)
      k_blk1<0><<<BATCH/16, 256, 0, stream>>>(xi, WoutT + (size_t)l*DM*DI, h,
          nw + (l+1)*DM, nullptr, nullptr, xn, nullptr);
    else
      k_blk1<1><<<BATCH/16, 256, 0, stream>>>(xi, WoutT + (size_t)l*DM*DI, h,
          nullptr, Wf, bf, nullptr, out);
  }
}